// Round 1
// 82.389 us; speedup vs baseline: 1.0900x; 1.0900x over previous
//
#include <hip/hip_runtime.h>
#include <math.h>

#define NG 1024      // gaussians per view
#define HH 128
#define WW 128
#define NV 2         // views
#define SH_C0 0.28209479177387814f
#define SH_C1 0.4886025119029199f

#define RECF 12                     // floats per gaussian record (3x float4)

#define TILE 8                      // 8x8 pixel tiles (was 16x16)
#define TPX  (WW/TILE)              // 16 tiles across
#define TPY  (HH/TILE)              // 16 tiles down
#define NT   (TPX*TPY)              // 256 tiles per view

// record layout (3x float4 per gaussian, depth-sorted):
//   rec0 = (u, v, dumax, dvmax)   -- position + exact alpha>=1/255 support bbox
//   rec1 = (A, B, C, pwmin)       -- conic, pre-negated/halved: pw = A du^2 + C dv^2 + B du dv
//   rec2 = (op, r, g, b)
// dumax = -1 marks an empty-support (skipped) gaussian.

// ---------------- Kernel A: fused preprocess + rank + sorted scatter ----------------
__global__ __launch_bounds__(256) void prep_rank_kernel(
    const float* __restrict__ xyz, const float* __restrict__ feats,
    const float* __restrict__ scaling, const float* __restrict__ rotation,
    const float* __restrict__ opacity, const float* __restrict__ C2W,
    const float* __restrict__ intr, float* __restrict__ ws)
{
    __shared__ unsigned long long s_key[NG];   // 8 KiB
    __shared__ int s_cnt[256];

    const int iv  = blockIdx.x >> 3;
    const int seg = blockIdx.x & 7;
    const int t   = threadIdx.x;

    const float* c2w = C2W + iv * 16;   // row-major 4x4
    // Rcw = R^T; row 2 of Rcw = column 2 of R
    const float r20 = c2w[2], r21 = c2w[6], r22 = c2w[10];
    const float tc2 = -(r20*c2w[3] + r21*c2w[7] + r22*c2w[11]);

    // ---- phase a: all 1024 depth keys of this view (4 contiguous per thread,
    //              xyz loaded as 3 aligned float4 instead of 12 scalar loads) ----
    {
        const float4* xyz4 = (const float4*)xyz;
        const float4 a0 = xyz4[t*3+0];
        const float4 a1 = xyz4[t*3+1];
        const float4 a2 = xyz4[t*3+2];
        const float xs[4] = {a0.x, a0.w, a1.z, a2.y};
        const float ys[4] = {a0.y, a1.x, a1.w, a2.z};
        const float zw[4] = {a0.z, a1.y, a2.x, a2.w};
        #pragma unroll
        for (int k = 0; k < 4; ++k) {
            const int g = t*4 + k;
            const float pz = r20*xs[k] + r21*ys[k] + r22*zw[k] + tc2;
            // valid => pz > 0.2 > 0; invalid => 1e5. IEEE bits strictly monotone in z.
            const float zk = (pz > 0.2f) ? pz : 100000.0f;
            s_key[g] = (((unsigned long long)__float_as_uint(zk)) << 10)
                     | (unsigned long long)(unsigned)g;
        }
    }
    __syncthreads();

    // ---- phase b: rank count (2 threads per gaussian, 512 keys each) ----
    const int g    = seg*128 + (t & 127);
    const int half = t >> 7;
    const unsigned long long ki = s_key[g];
    {
        const unsigned long long* kp = s_key + half*512;
        int cnt = 0;
        #pragma unroll 8
        for (int j = 0; j < 512; ++j)
            cnt += (kp[j] < ki) ? 1 : 0;
        s_cnt[t] = cnt;
    }
    __syncthreads();

    if (t >= 128) return;
    const int rank = s_cnt[t] + s_cnt[t+128];

    // ---- phase c: full preprocess for gaussian g, write to sorted slot ----
    const float fx = intr[iv*4+0], fy = intr[iv*4+1];
    const float cx = intr[iv*4+2], cy = intr[iv*4+3];

    float Rcw[3][3], tcw[3];
    #pragma unroll
    for (int r = 0; r < 3; ++r)
        #pragma unroll
        for (int c = 0; c < 3; ++c)
            Rcw[r][c] = c2w[c*4 + r];
    #pragma unroll
    for (int r = 0; r < 3; ++r)
        tcw[r] = -(Rcw[r][0]*c2w[3] + Rcw[r][1]*c2w[7] + Rcw[r][2]*c2w[11]);
    const float camx = c2w[3], camy = c2w[7], camz = c2w[11];

    const float X = xyz[g*3+0], Y = xyz[g*3+1], Z = xyz[g*3+2];

    // quaternion -> rotation (one float4 load)
    const float4 qv = ((const float4*)rotation)[g];
    float qw = qv.x, qx = qv.y, qy = qv.z, qz = qv.w;
    const float qn = rsqrtf(qw*qw + qx*qx + qy*qy + qz*qz);
    qw *= qn; qx *= qn; qy *= qn; qz *= qn;
    const float R00 = 1.f - 2.f*(qy*qy + qz*qz);
    const float R01 = 2.f*(qx*qy - qw*qz);
    const float R02 = 2.f*(qx*qz + qw*qy);
    const float R10 = 2.f*(qx*qy + qw*qz);
    const float R11 = 1.f - 2.f*(qx*qx + qz*qz);
    const float R12 = 2.f*(qy*qz - qw*qx);
    const float R20 = 2.f*(qx*qz - qw*qy);
    const float R21 = 2.f*(qy*qz + qw*qx);
    const float R22 = 1.f - 2.f*(qx*qx + qy*qy);

    const float s0 = scaling[g*3+0], s1 = scaling[g*3+1], s2 = scaling[g*3+2];
    const float M00 = R00*s0, M01 = R01*s1, M02 = R02*s2;
    const float M10 = R10*s0, M11 = R11*s1, M12 = R12*s2;
    const float M20 = R20*s0, M21 = R21*s1, M22 = R22*s2;

    // cov3d = M M^T (symmetric)
    const float S00 = M00*M00 + M01*M01 + M02*M02;
    const float S01 = M00*M10 + M01*M11 + M02*M12;
    const float S02 = M00*M20 + M01*M21 + M02*M22;
    const float S11 = M10*M10 + M11*M11 + M12*M12;
    const float S12 = M10*M20 + M11*M21 + M12*M22;
    const float S22 = M20*M20 + M21*M21 + M22*M22;

    // cov_cam = Rcw * S * Rcw^T
    float tmp[3][3];
    const float S[3][3] = {{S00,S01,S02},{S01,S11,S12},{S02,S12,S22}};
    #pragma unroll
    for (int r = 0; r < 3; ++r)
        #pragma unroll
        for (int c = 0; c < 3; ++c)
            tmp[r][c] = Rcw[r][0]*S[0][c] + Rcw[r][1]*S[1][c] + Rcw[r][2]*S[2][c];
    float C[3][3];
    #pragma unroll
    for (int r = 0; r < 3; ++r)
        #pragma unroll
        for (int c = 0; c < 3; ++c)
            C[r][c] = tmp[r][0]*Rcw[c][0] + tmp[r][1]*Rcw[c][1] + tmp[r][2]*Rcw[c][2];

    // camera-space x,y; z recovered from the key so ordering & projection agree
    const float px_ = Rcw[0][0]*X + Rcw[0][1]*Y + Rcw[0][2]*Z + tcw[0];
    const float py_ = Rcw[1][0]*X + Rcw[1][1]*Y + Rcw[1][2]*Z + tcw[1];
    const float zf  = __uint_as_float((unsigned)(ki >> 10));
    const bool valid = zf < 99999.0f;            // invalid marker is 1e5

    const float zs = fmaxf(zf, 0.2f);
    const float izs = 1.f / zs;

    const float u = fx*px_*izs + cx;
    const float v = fy*py_*izs + cy;

    // J rows: (a00, 0, a02), (0, a11, a12)
    const float a00 = fx*izs;
    const float a02 = -fx*px_*izs*izs;
    const float a11 = fy*izs;
    const float a12 = -fy*py_*izs*izs;

    const float c00 = a00*a00*C[0][0] + 2.f*a00*a02*C[0][2] + a02*a02*C[2][2] + 0.3f;
    const float c01 = a00*a11*C[0][1] + a00*a12*C[0][2] + a02*a11*C[1][2] + a02*a12*C[2][2];
    const float c11 = a11*a11*C[1][1] + 2.f*a11*a12*C[1][2] + a12*a12*C[2][2] + 0.3f;

    const float det = fmaxf(c00*c11 - c01*c01, 1e-6f);
    const float idet = 1.f / det;

    // SH color (degree 1); feats as 3 aligned float4 loads
    float dx = X - camx, dy = Y - camy, dz = Z - camz;
    const float dn = rsqrtf(dx*dx + dy*dy + dz*dz);
    dx *= dn; dy *= dn; dz *= dn;
    const float4* f4 = (const float4*)feats + g*3;   // [4][3] = 12 floats
    const float4 f0 = f4[0], f1 = f4[1], f2 = f4[2];
    // f[j][c]: f[0]=(f0.x,f0.y,f0.z) f[1]=(f0.w,f1.x,f1.y) f[2]=(f1.z,f1.w,f2.x) f[3]=(f2.y,f2.z,f2.w)
    float col[3];
    col[0] = fmaxf(SH_C0*f0.x - SH_C1*dy*f0.w + SH_C1*dz*f1.z - SH_C1*dx*f2.y + 0.5f, 0.f);
    col[1] = fmaxf(SH_C0*f0.y - SH_C1*dy*f1.x + SH_C1*dz*f1.w - SH_C1*dx*f2.z + 0.5f, 0.f);
    col[2] = fmaxf(SH_C0*f0.z - SH_C1*dy*f1.y + SH_C1*dz*f2.x - SH_C1*dx*f2.w + 0.5f, 0.f);

    const float op = valid ? opacity[g] : 0.f;
    const float pwmin = -logf(255.f * op);   // = -L; op=0 -> +inf -> always skipped

    // conic pre-negated/halved
    const float Aq = -0.5f * (c11*idet);
    const float Bq = c01*idet;
    const float Cq = -0.5f * (c00*idet);

    // Exact support bbox of {alpha >= 1/255}: du_max = sqrt(2L*c00),
    // dv_max = sqrt(2L*c11) (det never clamps: diag +0.3 => det_raw > 0.09).
    float dumax = -1.f, dvmax = -1.f;
    if (op >= (1.f/255.f)) {
        const float L = -pwmin;              // log(255*op) >= 0
        dumax = sqrtf(2.f*L*c00);
        dvmax = sqrtf(2.f*L*c11);
    }

    float4* dst = (float4*)(ws + (size_t)(iv*NG + rank)*RECF);
    dst[0] = make_float4(u,  v,  dumax, dvmax);
    dst[1] = make_float4(Aq, Bq, Cq,    pwmin);
    dst[2] = make_float4(op, col[0], col[1], col[2]);
}

// ---------------- Kernel B: tile-culled, depth-segment-parallel compositing ----------------
// grid = NV*NT blocks (one per 8x8 tile), 256 threads.
// 4 waves each own one depth-quarter of the culled list for all 64 pixels;
// partial (color, T) combined in depth order at the end (compositing is associative:
// (c1,T1) o (c2,T2) = (c1 + T1*c2, T1*T2)).
__global__ __launch_bounds__(256) void render_kernel(
    const float* __restrict__ ws, float* __restrict__ out)
{
    __shared__ unsigned short s_ids[NG];       // 2 KiB
    __shared__ int s_wsum[4];
    __shared__ float4 s_rec[NG*3];             // 48 KiB (worst-case full list)
    __shared__ float4 s_part[4][64];           // 4 KiB partial (r,g,b,T)

    const int iv   = blockIdx.x / NT;
    const int tile = blockIdx.x % NT;
    const int tx0  = (tile % TPX) * TILE;
    const int ty0  = (tile / TPX) * TILE;
    const int t    = threadIdx.x;
    const int lane = t & 63;
    const int wid  = t >> 6;

    const float xlo = tx0 + 0.5f, xhi = tx0 + TILE - 0.5f;
    const float ylo = ty0 + 0.5f, yhi = ty0 + TILE - 0.5f;

    const float4* recs = (const float4*)ws + (size_t)iv*NG*3;

    // ---- phase 1: bbox-cull 4 contiguous sorted records per thread (1 load each) ----
    int flags = 0, cnt = 0;
    #pragma unroll
    for (int k = 0; k < 4; ++k) {
        const int gidx = t*4 + k;
        const float4 g0 = recs[gidx*3+0];   // u,v,dumax,dvmax
        const bool hit = (g0.z >= 0.f)
                      && (g0.x - g0.z <= xhi) && (g0.x + g0.z >= xlo)
                      && (g0.y - g0.w <= yhi) && (g0.y + g0.w >= ylo);
        flags |= (hit ? 1 : 0) << k;
        cnt   += hit ? 1 : 0;
    }

    // ---- phase 2: order-preserving compaction via wave-shuffle prefix scan ----
    int v = cnt;
    #pragma unroll
    for (int d = 1; d < 64; d <<= 1) {
        const int n = __shfl_up(v, d, 64);
        if (lane >= d) v += n;
    }
    if (lane == 63) s_wsum[wid] = v;        // wave totals
    __syncthreads();
    int waveOff = 0;
    #pragma unroll
    for (int w = 0; w < 4; ++w)
        if (w < wid) waveOff += s_wsum[w];
    const int m = s_wsum[0] + s_wsum[1] + s_wsum[2] + s_wsum[3];
    int base = waveOff + v - cnt;           // exclusive prefix, global gidx order
    #pragma unroll
    for (int k = 0; k < 4; ++k) {
        if (flags & (1 << k)) s_ids[base++] = (unsigned short)(t*4 + k);
    }
    __syncthreads();

    // ---- phase 3: stage ALL m culled records into LDS (m <= 1024) ----
    for (int idx = t; idx < m*3; idx += 256) {
        const int rid = s_ids[idx/3];
        s_rec[idx] = recs[rid*3 + idx%3];
    }
    __syncthreads();

    // ---- phase 4: 4-way depth-segment composite; wave w = segment w, lane = pixel ----
    const float gx = tx0 + (lane & (TILE-1)) + 0.5f;
    const float gy = ty0 + (lane >> 3) + 0.5f;

    const int q  = (m + 3) >> 2;            // segment length
    const int j0 = wid * q;
    const int j1 = min(j0 + q, m);

    float T = 1.f, ar = 0.f, ag = 0.f, ab = 0.f;
    for (int j = j0; j < j1; ++j) {
        const float4 g0 = s_rec[j*3+0];   // u,v,-,-
        const float4 g1 = s_rec[j*3+1];   // A,B,C,pwmin
        const float du = gx - g0.x;
        const float dv = gy - g0.y;
        const float pw = fmaf(g1.x, du*du, fmaf(g1.z, dv*dv, g1.y*(du*dv)));
        if (pw <= 0.f && pw >= g1.w) {
            const float4 g2 = s_rec[j*3+2];  // op,r,g,b
            const float al = fminf(0.99f, g2.x * __expf(pw));
            if (al >= (1.f/255.f)) {
                const float w = al * T;
                ar += w * g2.y;
                ag += w * g2.z;
                ab += w * g2.w;
                T *= (1.f - al);
                if (T < 1e-5f) break;   // segment-local transmittance dead
            }
        }
    }
    s_part[wid][lane] = make_float4(ar, ag, ab, T);
    __syncthreads();

    // ---- phase 5: in-order combine of the 4 segment partials, write out ----
    if (t < 64) {
        const float4 p0 = s_part[0][t];
        const float4 p1 = s_part[1][t];
        const float4 p2 = s_part[2][t];
        const float4 p3 = s_part[3][t];
        float Ta = p0.w;
        float r = p0.x + Ta*p1.x;
        float g = p0.y + Ta*p1.y;
        float b = p0.z + Ta*p1.z;
        Ta *= p1.w;
        r += Ta*p2.x; g += Ta*p2.y; b += Ta*p2.z;
        Ta *= p2.w;
        r += Ta*p3.x; g += Ta*p3.y; b += Ta*p3.z;
        const int px = tx0 + (t & (TILE-1));
        const int py = ty0 + (t >> 3);
        out[((iv*3 + 0)*HH + py)*WW + px] = r;
        out[((iv*3 + 1)*HH + py)*WW + px] = g;
        out[((iv*3 + 2)*HH + py)*WW + px] = b;
    }
}

extern "C" void kernel_launch(void* const* d_in, const int* in_sizes, int n_in,
                              void* d_out, int out_size, void* d_ws, size_t ws_size,
                              hipStream_t stream) {
    const float* xyz      = (const float*)d_in[0];
    const float* feats    = (const float*)d_in[1];
    const float* scaling  = (const float*)d_in[2];
    const float* rotation = (const float*)d_in[3];
    const float* opacity  = (const float*)d_in[4];
    // d_in[5] = height, d_in[6] = width (fixed 128x128)
    const float* C2W      = (const float*)d_in[7];
    const float* intr     = (const float*)d_in[8];

    float* ws  = (float*)d_ws;    // needs NV*NG*12*4 = 96 KiB
    float* out = (float*)d_out;

    prep_rank_kernel<<<NV*8, 256, 0, stream>>>(
        xyz, feats, scaling, rotation, opacity, C2W, intr, ws);

    render_kernel<<<NV*NT, 256, 0, stream>>>(ws, out);
}